// Round 19
// baseline (197.229 us; speedup 1.0000x reference)
//
#include <hip/hip_runtime.h>
#include <math.h>

#define B_   8
#define T_   4096
#define D_   1024
#define H_   8
#define BW_  128
#define TC_  32
#define NC_  (T_/TC_)   // 128 chunks
#define NT_  4          // token-tiles (64 tok) per K1 block -> 1024 blocks = 4/CU

typedef __attribute__((ext_vector_type(8)))  short bf16x8;
typedef __attribute__((ext_vector_type(16))) float f32x16;
typedef __attribute__((ext_vector_type(4)))  unsigned short u16x4;

__device__ __forceinline__ unsigned short f2bf(float f) {
    unsigned int u = __float_as_uint(f);
    unsigned int r = (u + 0x7fffu + ((u >> 16) & 1u)) >> 16;
    return (unsigned short)r;
}
__device__ __forceinline__ float bf2f(unsigned short h) {
    return __uint_as_float(((unsigned int)h) << 16);
}
__device__ __forceinline__ float fast_exp(float x) {           // e^x
    return __builtin_amdgcn_exp2f(x * 1.4426950408889634f);
}
__device__ __forceinline__ float fast_rcp(float x) {
    return __builtin_amdgcn_rcpf(x);
}
__device__ __forceinline__ float fast_sqrt(float x) {
    return __builtin_amdgcn_sqrtf(x);
}
// unpack helpers for the (la, n) u32: lo16 = la bf16, hi16 = n bf16
__device__ __forceinline__ float up_n(unsigned int u)  {
    return __uint_as_float(u & 0xffff0000u);
}
__device__ __forceinline__ float up_a(unsigned int u)  {
    return fast_exp(__uint_as_float(u << 16));
}

// ---------------------------------------------------------------------------
// K0: W -> W^T, bf16 hi plane only (2-term A-split; R11 vetted absmax 1.0).
// ---------------------------------------------------------------------------
__global__ __launch_bounds__(256) void k0_wprep(
    const float* __restrict__ igw, const float* __restrict__ agw,
    unsigned short* __restrict__ wtIh, unsigned short* __restrict__ wtAh)
{
    const int h   = blockIdx.x >> 3;
    const int seg = blockIdx.x & 7;
    const float* wi = igw + ((size_t)h << 14);
    const float* wa = agw + ((size_t)h << 14);
    #pragma unroll
    for (int j = 0; j < 8; ++j) {
        int idx = seg * 2048 + threadIdx.x + 256 * j;   // [k][c]
        int k = idx >> 7, c = idx & 127;
        int o = (h << 14) + (c << 7) + k;               // [h][c][k]
        wtIh[o] = f2bf(wi[idx]);
        wtAh[o] = f2bf(wa[idx]);
    }
}

// ---------------------------------------------------------------------------
// K1: 2-term A-split MFMA (x hi/lo x B-hi) + token-group-split K-loop.
// REGISTER-FOOTPRINT DESIGN (R18 lesson: unified VGPR/AGPR file; R9's
// 128 frag VGPR + 64 acc AGPR = 192 -> hard 2 waves/SIMD cap):
//   frags 64 VGPR + live acc 32 AGPR + misc ~25 => ~120 total -> 4 waves/SIMD.
// tg=0,1 run as sequential K-loop+epilogue passes so only one tg's acc lives.
// grid (16, 8, 8) = 1024 blocks = 4 blocks/CU supplies the waves.
// launch_bounds stays (256,2): never squeeze the allocator (R10/R11).
// ---------------------------------------------------------------------------
__global__ __launch_bounds__(256, 2) void k1_gates_mfma(
    const float* __restrict__ x,
    const unsigned short* __restrict__ wtIh, const unsigned short* __restrict__ wtAh,
    const float* __restrict__ igb, const float* __restrict__ agb,
    const float* __restrict__ ap,
    unsigned int* __restrict__ anArr, float* __restrict__ PA)
{
    __shared__ unsigned short xs_hi[64][128];   // 16 KB, col ^= (row&7)<<3
    __shared__ unsigned short xs_lo[64][128];   // 16 KB

    const int tg0 = blockIdx.x;          // tile-group: tiles tg0*NT_ .. +NT_-1
    const int h   = blockIdx.y;
    const int b   = blockIdx.z;
    const int tid = threadIdx.x;

    const int cb = tid >> 6;     // wave -> 32-col block
    const int l  = tid & 63;
    const int lr = l & 31;
    const int hl = l >> 5;

    // ---- hoist B-fragments into registers (once per block, 64 VGPRs) ----
    const size_t wtoff = ((size_t)h << 14) + (size_t)(cb * 32 + lr) * 128 + hl * 8;
    const unsigned short* pIh = wtIh + wtoff;
    const unsigned short* pAh = wtAh + wtoff;
    bf16x8 fIh[8], fAh[8];
    #pragma unroll
    for (int ks = 0; ks < 8; ++ks) {
        fIh[ks] = *(const bf16x8*)(pIh + ks * 16);
        fAh[ks] = *(const bf16x8*)(pAh + ks * 16);
    }

    // per-channel constants
    const int d = h * BW_ + cb * 32 + lr;
    const float bI = igb[d], bA = agb[d];
    const float sp = log1pf(expf(ap[d]));    // accurate, once per thread

    for (int nt = 0; nt < NT_; ++nt) {
        const int tc = tg0 * NT_ + nt;       // 64-token tile index
        const int t0 = tc * 64;

        // stage x[b, t0:t0+64, h*128:(h+1)*128] -> bf16 hi/lo LDS (swizzled)
        const float* xbase = x + ((size_t)b * T_ + t0) * D_ + h * BW_;
        #pragma unroll
        for (int i = 0; i < 8; ++i) {
            int idx = tid + 256 * i;          // 2048 float4 slots
            int row = idx >> 5, c4 = idx & 31;
            float4 v = *(const float4*)(xbase + (size_t)row * D_ + c4 * 4);
            int col0 = (c4 * 4) ^ ((row & 7) << 3);
            u16x4 hv, lv;
            hv.x = f2bf(v.x); lv.x = f2bf(v.x - bf2f(hv.x));
            hv.y = f2bf(v.y); lv.y = f2bf(v.y - bf2f(hv.y));
            hv.z = f2bf(v.z); lv.z = f2bf(v.z - bf2f(hv.z));
            hv.w = f2bf(v.w); lv.w = f2bf(v.w - bf2f(hv.w));
            *(u16x4*)&xs_hi[row][col0] = hv;
            *(u16x4*)&xs_lo[row][col0] = lv;
        }
        __syncthreads();

        const size_t obase = ((size_t)b * T_ + t0) * D_ + d;

        // ---- two sequential passes: only ONE token-group's acc is live ----
        #pragma unroll
        for (int tg = 0; tg < 2; ++tg) {
            f32x16 aI, aA;
            #pragma unroll
            for (int i = 0; i < 16; ++i) { aI[i] = 0.f; aA[i] = 0.f; }

            const int rbase = tg * 32 + lr;
            #pragma unroll
            for (int ks = 0; ks < 8; ++ks) {
                const int k0 = ks * 16 + hl * 8;
                const int kk = k0 ^ ((lr & 7) << 3);
                bf16x8 xh = *(const bf16x8*)&xs_hi[rbase][kk];
                bf16x8 xl = *(const bf16x8*)&xs_lo[rbase][kk];

                aI = __builtin_amdgcn_mfma_f32_32x32x16_bf16(xh, fIh[ks], aI, 0, 0, 0);
                aA = __builtin_amdgcn_mfma_f32_32x32x16_bf16(xh, fAh[ks], aA, 0, 0, 0);
                aI = __builtin_amdgcn_mfma_f32_32x32x16_bf16(xl, fIh[ks], aI, 0, 0, 0);
                aA = __builtin_amdgcn_mfma_f32_32x32x16_bf16(xl, fAh[ks], aA, 0, 0, 0);
            }

            // epilogue for this token group; pack (la, n) -> one u32/elem.
            // C layout col=lane&31, row=(r&3)+8*(r>>2)+4*hl
            float pr = 1.f;
            #pragma unroll
            for (int r = 0; r < 16; ++r) {
                float yI = aI[r] + bI;
                float yA = aA[r] + bA;
                int row = (r & 3) + ((r >> 2) << 3) + 4 * hl;     // 0..31
                float gx = fast_rcp(1.f + fast_exp(-yI));
                float ga = fast_rcp(1.f + fast_exp(-yA));
                float la = -8.f * ga * sp;
                unsigned short lab = f2bf(la);      // store rounded log-a
                float av = fast_exp(bf2f(lab));     // a from ROUNDED la
                float mu = fast_sqrt(fmaxf(1.f - av * av, 1e-7f));
                int colx = (cb * 32 + lr) ^ ((row & 7) << 3);
                int rg = tg * 32 + row;
                float xv = bf2f(xs_hi[rg][colx]) + bf2f(xs_lo[rg][colx]);
                float nv = xv * gx * mu;
                pr *= av;
                anArr[obase + (size_t)rg * D_] =
                    ((unsigned int)f2bf(nv) << 16) | lab;
            }
            float q = pr * __shfl_xor(pr, 32, 64);   // product over 32 tokens
            if (hl == 0) {
                PA[((size_t)(tc * 2 + tg) * B_ + b) * D_ + d] = q;
            }
        }
        __syncthreads();   // xs reads done before next tile overwrites
    }
}

// ---------------------------------------------------------------------------
// K2: exclusive running product over chunks -> P_in per (chunk, channel).
// ---------------------------------------------------------------------------
__global__ void k2_pin(const float* __restrict__ PA, float* __restrict__ Pin)
{
    int id = blockIdx.x * 256 + threadIdx.x;    // b*D+d
    float P = 1.f;
    for (int cidx = 0; cidx < NC_; ++cidx) {
        Pin[(size_t)cidx * B_ * D_ + id] = P;
        P *= PA[(size_t)cidx * B_ * D_ + id];
    }
}

// ---------------------------------------------------------------------------
// K3: Wsum only (read-only pass over packed an). grid (NC, B), 256 thr.
// ---------------------------------------------------------------------------
__global__ __launch_bounds__(256) void k3_wsum(
    const unsigned int* __restrict__ anArr,
    const float* __restrict__ Pin, float* __restrict__ Wsum)
{
    const int cidx = blockIdx.x, b = blockIdx.y;
    const int tid = threadIdx.x;
    float P[4], W[4];
    #pragma unroll
    for (int j = 0; j < 4; ++j) {
        P[j] = Pin[((size_t)cidx * B_ + b) * D_ + tid + 256 * j];
        W[j] = 0.f;
    }
    const size_t base = ((size_t)b * T_ + cidx * TC_) * D_ + tid;
    for (int i = 0; i < TC_; ++i) {
        #pragma unroll
        for (int j = 0; j < 4; ++j) {
            size_t o = base + (size_t)i * D_ + 256 * j;
            unsigned int u = anArr[o];
            float n = up_n(u);
            float a = up_a(u);
            float pp = fmaxf(P[j], 1e-7f);
            W[j] += n / pp;
            P[j] *= a;
        }
    }
    #pragma unroll
    for (int j = 0; j < 4; ++j)
        Wsum[((size_t)cidx * B_ + b) * D_ + tid + 256 * j] = W[j];
}

// ---------------------------------------------------------------------------
// K4: exclusive running sum over chunks -> S_in per (chunk, channel).
// ---------------------------------------------------------------------------
__global__ void k4_sin(const float* __restrict__ Wsum, float* __restrict__ Sin)
{
    int id = blockIdx.x * 256 + threadIdx.x;
    float S = 0.f;
    for (int cidx = 0; cidx < NC_; ++cidx) {
        Sin[(size_t)cidx * B_ * D_ + id] = S;
        S += Wsum[(size_t)cidx * B_ * D_ + id];
    }
}

// ---------------------------------------------------------------------------
// K5: recompute pp,w from packed an + Pin; h = pp * (Sin + cumsum w).
// Bit-identical unpack + op order to K3's walk. grid (NC, B).
// ---------------------------------------------------------------------------
__global__ __launch_bounds__(256) void k5_final(
    const unsigned int* __restrict__ anArr,
    const float* __restrict__ Pin, const float* __restrict__ Sin,
    float* __restrict__ hOut)
{
    const int cidx = blockIdx.x, b = blockIdx.y;
    const int tid = threadIdx.x;
    float P[4], S[4];
    #pragma unroll
    for (int j = 0; j < 4; ++j) {
        P[j] = Pin[((size_t)cidx * B_ + b) * D_ + tid + 256 * j];
        S[j] = Sin[((size_t)cidx * B_ + b) * D_ + tid + 256 * j];
    }
    const size_t base = ((size_t)b * T_ + cidx * TC_) * D_ + tid;
    for (int i = 0; i < TC_; ++i) {
        #pragma unroll
        for (int j = 0; j < 4; ++j) {
            size_t o = base + (size_t)i * D_ + 256 * j;
            unsigned int u = anArr[o];
            float n = up_n(u);
            float a = up_a(u);
            float pp = fmaxf(P[j], 1e-7f);
            float w = n / pp;
            S[j] += w;
            hOut[o] = pp * S[j];
            P[j] *= a;
        }
    }
}

// Sentinel: if ws is too small, surface ws_size through the absmax report.
__global__ void k_sentinel(float* out, float v)
{
    if (threadIdx.x == 0 && blockIdx.x == 0) out[0] = v;
}

extern "C" void kernel_launch(void* const* d_in, const int* in_sizes, int n_in,
                              void* d_out, int out_size, void* d_ws, size_t ws_size,
                              hipStream_t stream)
{
    const float* x   = (const float*)d_in[0];
    const float* igw = (const float*)d_in[1];
    const float* igb = (const float*)d_in[2];
    const float* agw = (const float*)d_in[3];
    const float* agb = (const float*)d_in[4];
    const float* ap  = (const float*)d_in[5];
    float* hOut = (float*)d_out;

    const size_t elems = (size_t)B_ * T_ * D_;      // 33.5M
    const size_t agg   = (size_t)NC_ * B_ * D_;     // 1.05M
    const size_t needB = (elems + 4 * agg) * sizeof(float);  // ~151 MB

    if (ws_size < needB) {
        k_sentinel<<<1, 64, 0, stream>>>(hOut, (float)ws_size);
        return;
    }

    unsigned int* anArr = (unsigned int*)d_ws;
    float* PA   = (float*)(anArr + elems);
    float* Pin  = PA   + agg;
    float* Wsum = Pin  + agg;
    float* Sin  = Wsum + agg;

    // WT bf16 planes aliased into the Pin region (0.5 MB of its 4 MB).
    // K2 writes Pin only after K1 has consumed WT (stream-ordered) — safe.
    unsigned short* wtIh = (unsigned short*)Pin;
    unsigned short* wtAh = wtIh + 131072;

    k0_wprep<<<dim3(64), 256, 0, stream>>>(igw, agw, wtIh, wtAh);

    dim3 g1(T_ / 64 / NT_, H_, B_);     // (16, 8, 8) = 1024 blocks = 4/CU
    k1_gates_mfma<<<g1, 256, 0, stream>>>(x, wtIh, wtAh,
                                          igb, agb, ap, anArr, PA);

    k2_pin<<<dim3((B_ * D_) / 256), 256, 0, stream>>>(PA, Pin);

    k3_wsum<<<dim3(NC_, B_), 256, 0, stream>>>(anArr, Pin, Wsum);

    k4_sin<<<dim3((B_ * D_) / 256), 256, 0, stream>>>(Wsum, Sin);

    k5_final<<<dim3(NC_, B_), 256, 0, stream>>>(anArr, Pin, Sin, hOut);
}

// Round 20
// 184.857 us; speedup vs baseline: 1.0669x; 1.0669x over previous
//
#include <hip/hip_runtime.h>
#include <math.h>

#define B_   8
#define T_   4096
#define D_   1024
#define H_   8
#define BW_  128
#define TC_  32
#define NC_  (T_/TC_)   // 128 chunks
#define NT_  8          // token-tiles (64 tok) per K1 block

typedef __attribute__((ext_vector_type(8)))  short bf16x8;
typedef __attribute__((ext_vector_type(16))) float f32x16;
typedef __attribute__((ext_vector_type(4)))  unsigned short u16x4;

__device__ __forceinline__ unsigned short f2bf(float f) {
    unsigned int u = __float_as_uint(f);
    unsigned int r = (u + 0x7fffu + ((u >> 16) & 1u)) >> 16;
    return (unsigned short)r;
}
__device__ __forceinline__ float bf2f(unsigned short h) {
    return __uint_as_float(((unsigned int)h) << 16);
}
__device__ __forceinline__ float fast_exp(float x) {           // e^x
    return __builtin_amdgcn_exp2f(x * 1.4426950408889634f);
}
__device__ __forceinline__ float fast_rcp(float x) {
    return __builtin_amdgcn_rcpf(x);
}
__device__ __forceinline__ float fast_sqrt(float x) {
    return __builtin_amdgcn_sqrtf(x);
}
// unpack helpers for the (la, n) u32: lo16 = la bf16, hi16 = n bf16
__device__ __forceinline__ float up_n(unsigned int u)  {
    return __uint_as_float(u & 0xffff0000u);
}
__device__ __forceinline__ float up_a(unsigned int u)  {
    return fast_exp(__uint_as_float(u << 16));
}

// ---------------------------------------------------------------------------
// K0: W -> W^T, split into bf16 hi/lo planes: WT[h][col][k].
// ---------------------------------------------------------------------------
__global__ __launch_bounds__(256) void k0_wprep(
    const float* __restrict__ igw, const float* __restrict__ agw,
    unsigned short* __restrict__ wtIh, unsigned short* __restrict__ wtIl,
    unsigned short* __restrict__ wtAh, unsigned short* __restrict__ wtAl)
{
    const int h   = blockIdx.x >> 3;
    const int seg = blockIdx.x & 7;
    const float* wi = igw + ((size_t)h << 14);
    const float* wa = agw + ((size_t)h << 14);
    #pragma unroll
    for (int j = 0; j < 8; ++j) {
        int idx = seg * 2048 + threadIdx.x + 256 * j;   // [k][c]
        int k = idx >> 7, c = idx & 127;
        int o = (h << 14) + (c << 7) + k;               // [h][c][k]
        float vI = wi[idx], vA = wa[idx];
        unsigned short ih = f2bf(vI); unsigned short il = f2bf(vI - bf2f(ih));
        unsigned short ah = f2bf(vA); unsigned short al = f2bf(vA - bf2f(ah));
        wtIh[o] = ih; wtIl[o] = il; wtAh[o] = ah; wtAl[o] = al;
    }
}

// ---------------------------------------------------------------------------
// K1: gates via split-bf16 MFMA (32x32x16). B-fragments hoisted to registers
// ONCE per block; block loops over NT_ 64-token tiles of the same head.
// grid (T/64/NT, H, B) = (8, 8, 8), 256 threads = 4 waves; wave = 32-col blk.
// FINAL (R9 config, validated 3x): the {128-VGPR frag hoist, 4-chain acc ILP,
// 2 blk/CU residency} equilibrium. Seven counter-gated experiments (R7, R10,
// R11, R12, R14, R18, R19) each confirmed moves off this point regress:
// more waves break the hoist or the ILP; prefetch regs spill; epilogue
// aggregation costs more than the pass it saves.
// ---------------------------------------------------------------------------
__global__ __launch_bounds__(256, 2) void k1_gates_mfma(
    const float* __restrict__ x,
    const unsigned short* __restrict__ wtIh, const unsigned short* __restrict__ wtIl,
    const unsigned short* __restrict__ wtAh, const unsigned short* __restrict__ wtAl,
    const float* __restrict__ igb, const float* __restrict__ agb,
    const float* __restrict__ ap,
    unsigned int* __restrict__ anArr, float* __restrict__ PA)
{
    __shared__ unsigned short xs_hi[64][128];   // 16 KB, col ^= (row&7)<<3
    __shared__ unsigned short xs_lo[64][128];   // 16 KB

    const int tg0 = blockIdx.x;          // tile-group: tiles tg0*NT_ .. +NT_-1
    const int h   = blockIdx.y;
    const int b   = blockIdx.z;
    const int tid = threadIdx.x;

    const int cb = tid >> 6;     // wave -> 32-col block
    const int l  = tid & 63;
    const int lr = l & 31;
    const int hl = l >> 5;

    // ---- hoist all B-fragments into registers (once per block) ----
    const size_t wtoff = ((size_t)h << 14) + (size_t)(cb * 32 + lr) * 128 + hl * 8;
    const unsigned short* pIh = wtIh + wtoff;
    const unsigned short* pIl = wtIl + wtoff;
    const unsigned short* pAh = wtAh + wtoff;
    const unsigned short* pAl = wtAl + wtoff;
    bf16x8 fIh[8], fIl[8], fAh[8], fAl[8];
    #pragma unroll
    for (int ks = 0; ks < 8; ++ks) {
        fIh[ks] = *(const bf16x8*)(pIh + ks * 16);
        fIl[ks] = *(const bf16x8*)(pIl + ks * 16);
        fAh[ks] = *(const bf16x8*)(pAh + ks * 16);
        fAl[ks] = *(const bf16x8*)(pAl + ks * 16);
    }

    // per-channel constants
    const int d = h * BW_ + cb * 32 + lr;
    const float bI = igb[d], bA = agb[d];
    const float sp = log1pf(expf(ap[d]));    // accurate, once per thread

    for (int nt = 0; nt < NT_; ++nt) {
        const int tc = tg0 * NT_ + nt;       // 64-token tile index
        const int t0 = tc * 64;

        // stage x[b, t0:t0+64, h*128:(h+1)*128] -> bf16 hi/lo LDS (swizzled)
        const float* xbase = x + ((size_t)b * T_ + t0) * D_ + h * BW_;
        #pragma unroll
        for (int i = 0; i < 8; ++i) {
            int idx = tid + 256 * i;          // 2048 float4 slots
            int row = idx >> 5, c4 = idx & 31;
            float4 v = *(const float4*)(xbase + (size_t)row * D_ + c4 * 4);
            int col0 = (c4 * 4) ^ ((row & 7) << 3);
            u16x4 hv, lv;
            hv.x = f2bf(v.x); lv.x = f2bf(v.x - bf2f(hv.x));
            hv.y = f2bf(v.y); lv.y = f2bf(v.y - bf2f(hv.y));
            hv.z = f2bf(v.z); lv.z = f2bf(v.z - bf2f(hv.z));
            hv.w = f2bf(v.w); lv.w = f2bf(v.w - bf2f(hv.w));
            *(u16x4*)&xs_hi[row][col0] = hv;
            *(u16x4*)&xs_lo[row][col0] = lv;
        }
        __syncthreads();

        f32x16 aI0, aI1, aA0, aA1;
        #pragma unroll
        for (int i = 0; i < 16; ++i) { aI0[i]=0.f; aI1[i]=0.f; aA0[i]=0.f; aA1[i]=0.f; }

        #pragma unroll
        for (int ks = 0; ks < 8; ++ks) {
            const int k0 = ks * 16 + hl * 8;
            const int kk = k0 ^ ((lr & 7) << 3);
            bf16x8 xh0 = *(const bf16x8*)&xs_hi[lr][kk];
            bf16x8 xl0 = *(const bf16x8*)&xs_lo[lr][kk];
            bf16x8 xh1 = *(const bf16x8*)&xs_hi[32 + lr][kk];
            bf16x8 xl1 = *(const bf16x8*)&xs_lo[32 + lr][kk];

            aI0 = __builtin_amdgcn_mfma_f32_32x32x16_bf16(xh0, fIh[ks], aI0, 0, 0, 0);
            aI0 = __builtin_amdgcn_mfma_f32_32x32x16_bf16(xl0, fIh[ks], aI0, 0, 0, 0);
            aI0 = __builtin_amdgcn_mfma_f32_32x32x16_bf16(xh0, fIl[ks], aI0, 0, 0, 0);

            aI1 = __builtin_amdgcn_mfma_f32_32x32x16_bf16(xh1, fIh[ks], aI1, 0, 0, 0);
            aI1 = __builtin_amdgcn_mfma_f32_32x32x16_bf16(xl1, fIh[ks], aI1, 0, 0, 0);
            aI1 = __builtin_amdgcn_mfma_f32_32x32x16_bf16(xh1, fIl[ks], aI1, 0, 0, 0);

            aA0 = __builtin_amdgcn_mfma_f32_32x32x16_bf16(xh0, fAh[ks], aA0, 0, 0, 0);
            aA0 = __builtin_amdgcn_mfma_f32_32x32x16_bf16(xl0, fAh[ks], aA0, 0, 0, 0);
            aA0 = __builtin_amdgcn_mfma_f32_32x32x16_bf16(xh0, fAl[ks], aA0, 0, 0, 0);

            aA1 = __builtin_amdgcn_mfma_f32_32x32x16_bf16(xh1, fAh[ks], aA1, 0, 0, 0);
            aA1 = __builtin_amdgcn_mfma_f32_32x32x16_bf16(xl1, fAh[ks], aA1, 0, 0, 0);
            aA1 = __builtin_amdgcn_mfma_f32_32x32x16_bf16(xh1, fAl[ks], aA1, 0, 0, 0);
        }

        // epilogue: fast-math gate chain; pack (la, n) -> one u32 store/elem.
        // C layout col=lane&31, row=(r&3)+8*(r>>2)+4*hl
        const size_t obase = ((size_t)b * T_ + t0) * D_ + d;
        float pr0 = 1.f, pr1 = 1.f;
        #pragma unroll
        for (int tg = 0; tg < 2; ++tg) {
            #pragma unroll
            for (int r = 0; r < 16; ++r) {
                float yI = (tg ? aI1[r] : aI0[r]) + bI;
                float yA = (tg ? aA1[r] : aA0[r]) + bA;
                int row = (r & 3) + ((r >> 2) << 3) + 4 * hl;     // 0..31
                float gx = fast_rcp(1.f + fast_exp(-yI));
                float ga = fast_rcp(1.f + fast_exp(-yA));
                float la = -8.f * ga * sp;
                unsigned short lab = f2bf(la);      // store rounded log-a
                float av = fast_exp(bf2f(lab));     // a from ROUNDED la
                float mu = fast_sqrt(fmaxf(1.f - av * av, 1e-7f));
                int colx = (cb * 32 + lr) ^ ((row & 7) << 3);
                int rg = tg * 32 + row;
                float xv = bf2f(xs_hi[rg][colx]) + bf2f(xs_lo[rg][colx]);
                float nv = xv * gx * mu;
                if (tg) pr1 *= av; else pr0 *= av;
                anArr[obase + (size_t)rg * D_] =
                    ((unsigned int)f2bf(nv) << 16) | lab;
            }
        }
        float q0 = pr0 * __shfl_xor(pr0, 32, 64);
        float q1 = pr1 * __shfl_xor(pr1, 32, 64);
        if (hl == 0) {
            PA[((size_t)(tc * 2)     * B_ + b) * D_ + d] = q0;
            PA[((size_t)(tc * 2 + 1) * B_ + b) * D_ + d] = q1;
        }
        __syncthreads();   // xs reads done before next tile overwrites
    }
}

// ---------------------------------------------------------------------------
// K2: exclusive running product over chunks -> P_in per (chunk, channel).
// ---------------------------------------------------------------------------
__global__ void k2_pin(const float* __restrict__ PA, float* __restrict__ Pin)
{
    int id = blockIdx.x * 256 + threadIdx.x;    // b*D+d
    float P = 1.f;
    for (int cidx = 0; cidx < NC_; ++cidx) {
        Pin[(size_t)cidx * B_ * D_ + id] = P;
        P *= PA[(size_t)cidx * B_ * D_ + id];
    }
}

// ---------------------------------------------------------------------------
// K3: Wsum only (read-only pass over packed an). grid (NC, B), 256 thr.
// ---------------------------------------------------------------------------
__global__ __launch_bounds__(256) void k3_wsum(
    const unsigned int* __restrict__ anArr,
    const float* __restrict__ Pin, float* __restrict__ Wsum)
{
    const int cidx = blockIdx.x, b = blockIdx.y;
    const int tid = threadIdx.x;
    float P[4], W[4];
    #pragma unroll
    for (int j = 0; j < 4; ++j) {
        P[j] = Pin[((size_t)cidx * B_ + b) * D_ + tid + 256 * j];
        W[j] = 0.f;
    }
    const size_t base = ((size_t)b * T_ + cidx * TC_) * D_ + tid;
    for (int i = 0; i < TC_; ++i) {
        #pragma unroll
        for (int j = 0; j < 4; ++j) {
            size_t o = base + (size_t)i * D_ + 256 * j;
            unsigned int u = anArr[o];
            float n = up_n(u);
            float a = up_a(u);
            float pp = fmaxf(P[j], 1e-7f);
            W[j] += n / pp;
            P[j] *= a;
        }
    }
    #pragma unroll
    for (int j = 0; j < 4; ++j)
        Wsum[((size_t)cidx * B_ + b) * D_ + tid + 256 * j] = W[j];
}

// ---------------------------------------------------------------------------
// K4: exclusive running sum over chunks -> S_in per (chunk, channel).
// ---------------------------------------------------------------------------
__global__ void k4_sin(const float* __restrict__ Wsum, float* __restrict__ Sin)
{
    int id = blockIdx.x * 256 + threadIdx.x;
    float S = 0.f;
    for (int cidx = 0; cidx < NC_; ++cidx) {
        Sin[(size_t)cidx * B_ * D_ + id] = S;
        S += Wsum[(size_t)cidx * B_ * D_ + id];
    }
}

// ---------------------------------------------------------------------------
// K5: recompute pp,w from packed an + Pin; h = pp * (Sin + cumsum w).
// Bit-identical unpack + op order to K3's walk. grid (NC, B).
// ---------------------------------------------------------------------------
__global__ __launch_bounds__(256) void k5_final(
    const unsigned int* __restrict__ anArr,
    const float* __restrict__ Pin, const float* __restrict__ Sin,
    float* __restrict__ hOut)
{
    const int cidx = blockIdx.x, b = blockIdx.y;
    const int tid = threadIdx.x;
    float P[4], S[4];
    #pragma unroll
    for (int j = 0; j < 4; ++j) {
        P[j] = Pin[((size_t)cidx * B_ + b) * D_ + tid + 256 * j];
        S[j] = Sin[((size_t)cidx * B_ + b) * D_ + tid + 256 * j];
    }
    const size_t base = ((size_t)b * T_ + cidx * TC_) * D_ + tid;
    for (int i = 0; i < TC_; ++i) {
        #pragma unroll
        for (int j = 0; j < 4; ++j) {
            size_t o = base + (size_t)i * D_ + 256 * j;
            unsigned int u = anArr[o];
            float n = up_n(u);
            float a = up_a(u);
            float pp = fmaxf(P[j], 1e-7f);
            float w = n / pp;
            S[j] += w;
            hOut[o] = pp * S[j];
            P[j] *= a;
        }
    }
}

// Sentinel: if ws is too small, surface ws_size through the absmax report.
__global__ void k_sentinel(float* out, float v)
{
    if (threadIdx.x == 0 && blockIdx.x == 0) out[0] = v;
}

extern "C" void kernel_launch(void* const* d_in, const int* in_sizes, int n_in,
                              void* d_out, int out_size, void* d_ws, size_t ws_size,
                              hipStream_t stream)
{
    const float* x   = (const float*)d_in[0];
    const float* igw = (const float*)d_in[1];
    const float* igb = (const float*)d_in[2];
    const float* agw = (const float*)d_in[3];
    const float* agb = (const float*)d_in[4];
    const float* ap  = (const float*)d_in[5];
    float* hOut = (float*)d_out;

    const size_t elems = (size_t)B_ * T_ * D_;      // 33.5M
    const size_t agg   = (size_t)NC_ * B_ * D_;     // 1.05M
    const size_t needB = (elems + 4 * agg) * sizeof(float);  // ~151 MB

    if (ws_size < needB) {
        k_sentinel<<<1, 64, 0, stream>>>(hOut, (float)ws_size);
        return;
    }

    unsigned int* anArr = (unsigned int*)d_ws;
    float* PA   = (float*)(anArr + elems);
    float* Pin  = PA   + agg;
    float* Wsum = Pin  + agg;
    float* Sin  = Wsum + agg;

    // WT bf16 planes aliased into the Pin region (1 MB of its 4 MB).
    // K2 writes Pin only after K1 has consumed WT (stream-ordered) — safe.
    unsigned short* wtIh = (unsigned short*)Pin;
    unsigned short* wtIl = wtIh + 131072;
    unsigned short* wtAh = wtIl + 131072;
    unsigned short* wtAl = wtAh + 131072;

    k0_wprep<<<dim3(64), 256, 0, stream>>>(igw, agw, wtIh, wtIl, wtAh, wtAl);

    dim3 g1(T_ / 64 / NT_, H_, B_);     // (8, 8, 8) = 512 blocks
    k1_gates_mfma<<<g1, 256, 0, stream>>>(x, wtIh, wtIl, wtAh, wtAl,
                                          igb, agb, ap, anArr, PA);

    k2_pin<<<dim3((B_ * D_) / 256), 256, 0, stream>>>(PA, Pin);

    k3_wsum<<<dim3(NC_, B_), 256, 0, stream>>>(anArr, Pin, Wsum);

    k4_sin<<<dim3((B_ * D_) / 256), 256, 0, stream>>>(Wsum, Sin);

    k5_final<<<dim3(NC_, B_), 256, 0, stream>>>(anArr, Pin, Sin, hOut);
}